// Round 10
// baseline (167.489 us; speedup 1.0000x reference)
//
#include <hip/hip_runtime.h>

// DualMem fast_get_image_pred:
//   logits[b,c] = 100 * (Σ_m w_m sim_m) / sqrt(Σ_{i,j} w_i w_j G[c,i,j])
//
// Lesson ledger (10 rounds):
//  - Spill signature = all-pipes-idle + scratch writes (WRITE_SIZE balloons).
//    Triggers: launch_bounds 2nd arg / 320-thr blocks / >=48KB LDS all starve
//    the allocator (64-88 VGPR); and ANY role whose {persistent + one load
//    batch} exceeds its allocation spills (R9: gram v[11]xfloat4=44 + g[17]
//    vs 80 VGPR -> 143MB scratch, 94us for 1us of math).
//    => keep live sets ~<=55, plain __launch_bounds__(256), no big LDS.
//  - R4: loads whose address ignores lane bits are wave-duplicated through
//    L1 (16x dup = 3.1GB = 105us). => lane-distinct addresses.
//  - R6/R9: grid (Cn, j) with Cn%8==0 keeps same-class siblings on one XCD
//    (FETCH 88->~50MB); sched_barrier(0) fences serialize load latency.
//
// Structure: 3 simple kernels, zero LDS in hot paths, no fences.
//   K1 sim:  grid(1000,4); wave owns 4 b-rows; lane l owns d=4l+256k.
//   K2 gram: grid(1000); 17-pair compile-time groups; float2 loads so the
//            per-k batch is 22 regs (was 44 -> spilled).
//   K3 finish: grid(250); trivial.

constexpr int Bn = 64;     // batch
constexpr int Cn = 1000;   // classes
constexpr int Mn = 11;     // memories per class
constexpr int Dn = 1024;   // feature dim
constexpr int NP = 66;     // Mn*(Mn+1)/2 unique Gram pairs
constexpr float BETA = 5.5f;

// p-th pair (i<=j) of the upper-triangular 11x11 Gram (compile-time p only!)
constexpr int pairI(int p) {
    int i = 0;
    while (p >= Mn - i) { p -= Mn - i; ++i; }
    return i;
}
constexpr int pairJ(int p) {
    int i = 0;
    while (p >= Mn - i) { p -= Mn - i; ++i; }
    return i + p;
}

// ---------------- K1: sim[c][b][m] (unchanged from R9) ----------------
__global__ __launch_bounds__(256) void sim_kernel(
    const float* __restrict__ img, const float* __restrict__ mem,
    float* __restrict__ sim) {
    const int c  = blockIdx.x;         // class; XCD = c%8 (1000%8==0 keeps
    const int jq = blockIdx.y;         // all 4 siblings of c on one XCD)
    const int w  = threadIdx.x >> 6;   // wave 0..3
    const int l  = threadIdx.x & 63;   // lane: d = 4*l + 256*k + {0..3}
    const int b0 = jq * 16 + w * 4;    // this wave's 4 b-rows

    const float* ip = img + b0 * Dn + 4 * l;
    const float* mp = mem + (size_t)c * (Mn * Dn) + 4 * l;

    float acc[4][Mn];
#pragma unroll
    for (int i = 0; i < 4; ++i)
#pragma unroll
        for (int m = 0; m < Mn; ++m) acc[i][m] = 0.f;

#pragma unroll 1
    for (int k = 0; k < 4; ++k) {      // unroll 1: bound transient pressure
        float4 iv[4];
#pragma unroll
        for (int i = 0; i < 4; ++i)
            iv[i] = *reinterpret_cast<const float4*>(ip + i * Dn + 256 * k);
#pragma unroll
        for (int m = 0; m < Mn; ++m) {
            const float4 mv = *reinterpret_cast<const float4*>(mp + m * Dn + 256 * k);
#pragma unroll
            for (int i = 0; i < 4; ++i) {
                float a = acc[i][m];
                a = fmaf(iv[i].x, mv.x, a);
                a = fmaf(iv[i].y, mv.y, a);
                a = fmaf(iv[i].z, mv.z, a);
                a = fmaf(iv[i].w, mv.w, a);
                acc[i][m] = a;
            }
        }
    }

    // full 64-lane butterfly reduce of each of the 44 partial dots
#pragma unroll
    for (int i = 0; i < 4; ++i)
#pragma unroll
        for (int m = 0; m < Mn; ++m) {
            float x = acc[i][m];
            x += __shfl_xor(x, 1, 64);
            x += __shfl_xor(x, 2, 64);
            x += __shfl_xor(x, 4, 64);
            x += __shfl_xor(x, 8, 64);
            x += __shfl_xor(x, 16, 64);
            x += __shfl_xor(x, 32, 64);
            acc[i][m] = x;
        }

    if (l == 0) {
        float* o = sim + (size_t)c * (Bn * Mn) + b0 * Mn;  // 44 contiguous floats
#pragma unroll
        for (int i = 0; i < 4; ++i)
#pragma unroll
            for (int m = 0; m < Mn; ++m) o[i * Mn + m] = acc[i][m];
    }
}

// ---------------- K2: gram[c][p] — float2 loads (anti-spill) ----------------
template <int P0, int P1>
__device__ inline void gramPairs2(const float2* v, float* g) {
#pragma unroll
    for (int p = P0; p < P1; ++p) {           // p compile-time after unroll
        const float2 a = v[pairI(p)];
        const float2 b = v[pairJ(p)];
        float x = g[p - P0];
        x = fmaf(a.x, b.x, x);
        x = fmaf(a.y, b.y, x);
        g[p - P0] = x;
    }
}

__global__ __launch_bounds__(256) void gram_kernel(
    const float* __restrict__ mem, float* __restrict__ gram) {
    const int c = blockIdx.x;
    const int w = threadIdx.x >> 6;    // wave: pair group
    const int l = threadIdx.x & 63;    // lane: d = 2*l + 128*k + {0,1}

    const float* mp = mem + (size_t)c * (Mn * Dn) + 2 * l;

    float g[17];
#pragma unroll
    for (int q = 0; q < 17; ++q) g[q] = 0.f;

#pragma unroll 1
    for (int k = 0; k < 8; ++k) {      // per-k batch: 11 float2 = 22 regs
        float2 v[Mn];
#pragma unroll
        for (int m = 0; m < Mn; ++m)
            v[m] = *reinterpret_cast<const float2*>(mp + m * Dn + 128 * k);
        if (w == 0)      gramPairs2<0, 17>(v, g);
        else if (w == 1) gramPairs2<17, 34>(v, g);
        else if (w == 2) gramPairs2<34, 50>(v, g);
        else             gramPairs2<50, 66>(v, g);
    }
#pragma unroll
    for (int q = 0; q < 17; ++q) {
        float x = g[q];
        x += __shfl_xor(x, 1, 64);
        x += __shfl_xor(x, 2, 64);
        x += __shfl_xor(x, 4, 64);
        x += __shfl_xor(x, 8, 64);
        x += __shfl_xor(x, 16, 64);
        x += __shfl_xor(x, 32, 64);
        g[q] = x;
    }
    const int np = (w < 2) ? 17 : 16;
    const int p0 = (w == 0) ? 0 : (w == 1) ? 17 : (w == 2) ? 34 : 50;
    if (l == 0) {
#pragma unroll
        for (int q = 0; q < 17; ++q)          // q compile-time, guard runtime
            if (q < np) gram[c * NP + p0 + q] = g[q];
    }
}

// ---------------- K3: logits (unchanged) ----------------
__global__ __launch_bounds__(256) void finish_kernel(
    const float* __restrict__ sim, const float* __restrict__ gram,
    float* __restrict__ out) {
    const int b = threadIdx.x & 63;
    const int c = blockIdx.x * 4 + (threadIdx.x >> 6);

    const float* sp = sim + (size_t)c * (Bn * Mn) + b * Mn;
    const float* gp = gram + c * NP;

    float w[Mn];
    float numer = 0.f;
#pragma unroll
    for (int m = 0; m < Mn; ++m) {
        const float s = sp[m];
        w[m]  = __expf(BETA * (s - 1.f));
        numer = fmaf(w[m], s, numer);
    }
    float den2 = 0.f;
#pragma unroll
    for (int p = 0; p < NP; ++p) {
        const float t = w[pairI(p)] * w[pairJ(p)] * gp[p];
        den2 += (pairI(p) == pairJ(p)) ? t : (2.f * t);
    }
    out[b * Cn + c] = 100.f * numer / sqrtf(den2);
}

extern "C" void kernel_launch(void* const* d_in, const int* in_sizes, int n_in,
                              void* d_out, int out_size, void* d_ws, size_t ws_size,
                              hipStream_t stream) {
    const float* img = (const float*)d_in[0];  // [64][1024] f32
    const float* mem = (const float*)d_in[1];  // [1000][11][1024] f32
    float* out = (float*)d_out;                // [64][1000] f32
    (void)in_sizes; (void)n_in; (void)out_size; (void)ws_size;

    float* ws_sim  = (float*)d_ws;             // [1000][64][11]
    float* ws_gram = ws_sim + Cn * Bn * Mn;    // [1000][66]

    sim_kernel<<<dim3(Cn, 4), dim3(256), 0, stream>>>(img, mem, ws_sim);
    gram_kernel<<<dim3(Cn), dim3(256), 0, stream>>>(mem, ws_gram);
    finish_kernel<<<dim3(Cn / 4), dim3(256), 0, stream>>>(ws_sim, ws_gram, out);
}

// Round 11
// 100.751 us; speedup vs baseline: 1.6624x; 1.6624x over previous
//
#include <hip/hip_runtime.h>

// DualMem fast_get_image_pred:
//   logits[b,c] = 100 * (Σ_m w_m sim_m) / sqrt(Σ_{i,j} w_i w_j G[c,i,j])
//
// Lesson ledger (11 rounds):
//  - Spill has TWO distinct triggers on this compiler:
//    (a) allocator starvation: launch_bounds 2nd arg / 320-thr / >=48KB LDS
//        => 64-88 VGPR regardless of need (R1/R5/R7/R8).
//    (b) ESCAPED LOCAL ARRAYS: passing a local array by pointer to a helper
//        (gramPairs(v, g)) allocates it in scratch — R9 float4 (143MB) and
//        R10 float2 (137MB) spilled IDENTICALLY despite 2x batch difference.
//        Rule #20 generalized: no local array may escape; no runtime
//        indexing. Safest: no local arrays at all in hot kernels.
//  - R4: loads whose address ignores lane bits are wave-duplicated through
//    L1 (16x dup). => lane-distinct addresses.
//  - R6/R9: grid (Cn, j) with Cn%8==0 keeps same-class siblings on one XCD;
//    never use sched_barrier(0) fences.
//
// Structure: 3 simple kernels, zero LDS in hot paths, no fences, no arrays
// in gram.
//   K1 sim:  grid(1000,4); wave owns 4 b-rows; lane l owns d=4l+256k.
//   K2 gram: grid(1000,17); ONE PAIR PER WAVE (~15 live regs, spill-proof).
//   K3 finish: grid(250); trivial.

constexpr int Bn = 64;     // batch
constexpr int Cn = 1000;   // classes
constexpr int Mn = 11;     // memories per class
constexpr int Dn = 1024;   // feature dim
constexpr int NP = 66;     // Mn*(Mn+1)/2 unique Gram pairs
constexpr float BETA = 5.5f;

// p-th pair (i<=j) of the upper-triangular 11x11 Gram (compile-time p only!)
constexpr int pairI(int p) {
    int i = 0;
    while (p >= Mn - i) { p -= Mn - i; ++i; }
    return i;
}
constexpr int pairJ(int p) {
    int i = 0;
    while (p >= Mn - i) { p -= Mn - i; ++i; }
    return i + p;
}

// ---------------- K1: sim[c][b][m] (unchanged from R9/R10) ----------------
__global__ __launch_bounds__(256) void sim_kernel(
    const float* __restrict__ img, const float* __restrict__ mem,
    float* __restrict__ sim) {
    const int c  = blockIdx.x;         // class; XCD = c%8 (1000%8==0 keeps
    const int jq = blockIdx.y;         // all 4 siblings of c on one XCD)
    const int w  = threadIdx.x >> 6;   // wave 0..3
    const int l  = threadIdx.x & 63;   // lane: d = 4*l + 256*k + {0..3}
    const int b0 = jq * 16 + w * 4;    // this wave's 4 b-rows

    const float* ip = img + b0 * Dn + 4 * l;
    const float* mp = mem + (size_t)c * (Mn * Dn) + 4 * l;

    float acc[4][Mn];
#pragma unroll
    for (int i = 0; i < 4; ++i)
#pragma unroll
        for (int m = 0; m < Mn; ++m) acc[i][m] = 0.f;

#pragma unroll 1
    for (int k = 0; k < 4; ++k) {      // unroll 1: bound transient pressure
        float4 iv[4];
#pragma unroll
        for (int i = 0; i < 4; ++i)
            iv[i] = *reinterpret_cast<const float4*>(ip + i * Dn + 256 * k);
#pragma unroll
        for (int m = 0; m < Mn; ++m) {
            const float4 mv = *reinterpret_cast<const float4*>(mp + m * Dn + 256 * k);
#pragma unroll
            for (int i = 0; i < 4; ++i) {
                float a = acc[i][m];
                a = fmaf(iv[i].x, mv.x, a);
                a = fmaf(iv[i].y, mv.y, a);
                a = fmaf(iv[i].z, mv.z, a);
                a = fmaf(iv[i].w, mv.w, a);
                acc[i][m] = a;
            }
        }
    }

    // full 64-lane butterfly reduce of each of the 44 partial dots
#pragma unroll
    for (int i = 0; i < 4; ++i)
#pragma unroll
        for (int m = 0; m < Mn; ++m) {
            float x = acc[i][m];
            x += __shfl_xor(x, 1, 64);
            x += __shfl_xor(x, 2, 64);
            x += __shfl_xor(x, 4, 64);
            x += __shfl_xor(x, 8, 64);
            x += __shfl_xor(x, 16, 64);
            x += __shfl_xor(x, 32, 64);
            acc[i][m] = x;
        }

    if (l == 0) {
        float* o = sim + (size_t)c * (Bn * Mn) + b0 * Mn;  // 44 contiguous floats
#pragma unroll
        for (int i = 0; i < 4; ++i)
#pragma unroll
            for (int m = 0; m < Mn; ++m) o[i * Mn + m] = acc[i][m];
    }
}

// ---------------- K2: gram[c][p] — one pair per wave, no arrays ----------------
__global__ __launch_bounds__(256) void gram_kernel(
    const float* __restrict__ mem, float* __restrict__ gram) {
    const int c    = blockIdx.x;
    const int w    = threadIdx.x >> 6;        // wave 0..3
    const int l    = threadIdx.x & 63;        // lane: d = 4*l + 256*k + {0..3}
    const int pidx = blockIdx.y * 4 + w;      // pair index 0..67
    if (pidx >= NP) return;                   // wave-uniform exit (slots 66,67)

    // decode pair (i<=j) — wave-uniform scalar loop, ~10 ops
    int i = 0, p = pidx;
    while (p >= Mn - i) { p -= Mn - i; ++i; }
    const int j = i + p;

    const float* ri = mem + (size_t)c * (Mn * Dn) + i * Dn + 4 * l;
    const float* rj = mem + (size_t)c * (Mn * Dn) + j * Dn + 4 * l;

    float acc = 0.f;
#pragma unroll
    for (int k = 0; k < 4; ++k) {
        const float4 a = *reinterpret_cast<const float4*>(ri + 256 * k);
        const float4 b = *reinterpret_cast<const float4*>(rj + 256 * k);
        acc = fmaf(a.x, b.x, acc);
        acc = fmaf(a.y, b.y, acc);
        acc = fmaf(a.z, b.z, acc);
        acc = fmaf(a.w, b.w, acc);
    }
    acc += __shfl_xor(acc, 1, 64);
    acc += __shfl_xor(acc, 2, 64);
    acc += __shfl_xor(acc, 4, 64);
    acc += __shfl_xor(acc, 8, 64);
    acc += __shfl_xor(acc, 16, 64);
    acc += __shfl_xor(acc, 32, 64);
    if (l == 0) gram[c * NP + pidx] = acc;
}

// ---------------- K3: logits (unchanged) ----------------
__global__ __launch_bounds__(256) void finish_kernel(
    const float* __restrict__ sim, const float* __restrict__ gram,
    float* __restrict__ out) {
    const int b = threadIdx.x & 63;
    const int c = blockIdx.x * 4 + (threadIdx.x >> 6);

    const float* sp = sim + (size_t)c * (Bn * Mn) + b * Mn;
    const float* gp = gram + c * NP;

    float w[Mn];
    float numer = 0.f;
#pragma unroll
    for (int m = 0; m < Mn; ++m) {
        const float s = sp[m];
        w[m]  = __expf(BETA * (s - 1.f));
        numer = fmaf(w[m], s, numer);
    }
    float den2 = 0.f;
#pragma unroll
    for (int p = 0; p < NP; ++p) {
        const float t = w[pairI(p)] * w[pairJ(p)] * gp[p];
        den2 += (pairI(p) == pairJ(p)) ? t : (2.f * t);
    }
    out[b * Cn + c] = 100.f * numer / sqrtf(den2);
}

extern "C" void kernel_launch(void* const* d_in, const int* in_sizes, int n_in,
                              void* d_out, int out_size, void* d_ws, size_t ws_size,
                              hipStream_t stream) {
    const float* img = (const float*)d_in[0];  // [64][1024] f32
    const float* mem = (const float*)d_in[1];  // [1000][11][1024] f32
    float* out = (float*)d_out;                // [64][1000] f32
    (void)in_sizes; (void)n_in; (void)out_size; (void)ws_size;

    float* ws_sim  = (float*)d_ws;             // [1000][64][11]
    float* ws_gram = ws_sim + Cn * Bn * Mn;    // [1000][66]

    sim_kernel<<<dim3(Cn, 4), dim3(256), 0, stream>>>(img, mem, ws_sim);
    gram_kernel<<<dim3(Cn, (NP + 3) / 4), dim3(256), 0, stream>>>(mem, ws_gram);
    finish_kernel<<<dim3(Cn / 4), dim3(256), 0, stream>>>(ws_sim, ws_gram, out);
}